// Round 2
// baseline (2273.777 us; speedup 1.0000x reference)
//
#include <hip/hip_runtime.h>

// BendingEnergy: fused 19-point stencil + per-batch mean reduction.
// f: (4, 160, 160, 160, 3) f32, c innermost. out: (4,) f32.
// Thread mapping: one thread per (b, x, y, m) with m = z*3 + c the fused
// contiguous axis -> all taps coalesced stride-4B across the wave.

#define DIM 160
#define NOUT 156               // 160 - 4
#define SX (160 * 160 * 3)     // x stride (elements)
#define SY (160 * 3)           // y stride
#define NM 468                 // valid m count per row: z in [2,158) x 3 channels
#define M0 6                   // first valid m = 2*3

__global__ __launch_bounds__(256) void bending_energy_kernel(
    const float* __restrict__ f, float* __restrict__ out) {
    const int b = blockIdx.y;
    const int NPTS = NOUT * NOUT * NM;           // 156*156*468 = 11,389,248
    int n = blockIdx.x * 256 + threadIdx.x;

    float e = 0.0f;
    if (n < NPTS) {
        int m = n % NM + M0;                     // fused (z,c) index
        int t = n / NM;
        int y = t % NOUT + 2;
        int x = t / NOUT + 2;
        const float* p = f + (long long)b * (DIM * DIM * DIM * 3)
                           + (long long)x * SX + y * SY + m;

        float ctr = p[0];
        float dxx = 0.25f * (p[2 * SX] - 2.0f * ctr + p[-2 * SX]);
        float dyy = 0.25f * (p[2 * SY] - 2.0f * ctr + p[-2 * SY]);
        float dzz = 0.25f * (p[6] - 2.0f * ctr + p[-6]);
        float dxy = 0.25f * (p[SX + SY] - p[-SX + SY] - p[SX - SY] + p[-SX - SY]);
        float dxz = 0.25f * (p[SX + 3] - p[-SX + 3] - p[SX - 3] + p[-SX - 3]);
        float dyz = 0.25f * (p[SY + 3] - p[-SY + 3] - p[SY - 3] + p[-SY - 3]);
        e = dxx * dxx + dyy * dyy + dzz * dzz
          + 2.0f * (dxy * dxy + dxz * dxz + dyz * dyz);
    }

    // wave-64 reduction
#pragma unroll
    for (int off = 32; off > 0; off >>= 1) e += __shfl_down(e, off, 64);

    __shared__ float ws[4];
    int lane = threadIdx.x & 63;
    int wid = threadIdx.x >> 6;
    if (lane == 0) ws[wid] = e;
    __syncthreads();
    if (threadIdx.x == 0) {
        float s = ws[0] + ws[1] + ws[2] + ws[3];
        const float inv_count = 1.0f / (156.0f * 156.0f * 156.0f * 3.0f);
        atomicAdd(&out[b], s * inv_count);
    }
}

extern "C" void kernel_launch(void* const* d_in, const int* in_sizes, int n_in,
                              void* d_out, int out_size, void* d_ws, size_t ws_size,
                              hipStream_t stream) {
    const float* f = (const float*)d_in[0];
    float* out = (float*)d_out;

    hipMemsetAsync(d_out, 0, out_size * sizeof(float), stream);

    const int NPTS = NOUT * NOUT * NM;           // 11,389,248
    dim3 block(256);
    dim3 grid((NPTS + 255) / 256, 4);
    bending_energy_kernel<<<grid, block, 0, stream>>>(f, out);
}

// Round 3
// 581.180 us; speedup vs baseline: 3.9123x; 3.9123x over previous
//
#include <hip/hip_runtime.h>

// BendingEnergy: fused 19-point stencil + per-batch mean reduction.
// f: (4, 160, 160, 160, 3) f32, c innermost (m = z*3+c fused, 480 per row).
// One thread = 4 consecutive m-outputs via float4 loads (all reg-resident).
// 1D grid ordered (mq, y, x, b) + bijective XCD chunking for L2 locality.

#define DIM 160
#define NOUT 156
#define SX (160 * 160 * 3)
#define SY (160 * 3)
#define NQ 117                      // m-quads per (x,y) row: 468/4
#define QPB 2847312                 // quads per batch: 156*156*117
#define B1 11128                    // blocks per batch (padded to %8==0)
#define NWG (4 * B1)                // 44512
#define NXCD 8
#define CPX (NWG / NXCD)            // 5564

typedef float F4 __attribute__((ext_vector_type(4)));

__device__ __forceinline__ F4 ld4(const float* p) {
    return *reinterpret_cast<const F4*>(p);
}

__global__ __launch_bounds__(256) void bending_energy_kernel(
    const float* __restrict__ f, float* __restrict__ out) {
    // bijective XCD-chunked swizzle: each XCD owns a contiguous block range
    int bid = blockIdx.x;
    int sid = (bid % NXCD) * CPX + bid / NXCD;
    int b = sid / B1;
    int n = (sid % B1) * 256 + threadIdx.x;   // quad index within batch

    float e = 0.0f;
    if (n < QPB) {
        int mq = n % NQ;
        int t = n / NQ;
        int y = t % NOUT + 2;
        int x = t / NOUT + 2;
        int m0 = 6 + 4 * mq;
        const float* p = f + (long long)b * (DIM * DIM * DIM * 3)
                           + (long long)x * SX + y * SY + m0;

        // center row: m0-6 .. m0+9 (16 floats)
        float c[16];
#pragma unroll
        for (int i = 0; i < 4; ++i)
            *reinterpret_cast<F4*>(&c[4 * i]) = ld4(p - 6 + 4 * i);
        // x+-1 rows: m0-3 .. m0+8 (12 floats)
        float xp[12], xm[12], yp[12], ym[12];
#pragma unroll
        for (int i = 0; i < 3; ++i) {
            *reinterpret_cast<F4*>(&xp[4 * i]) = ld4(p + SX - 3 + 4 * i);
            *reinterpret_cast<F4*>(&xm[4 * i]) = ld4(p - SX - 3 + 4 * i);
            *reinterpret_cast<F4*>(&yp[4 * i]) = ld4(p + SY - 3 + 4 * i);
            *reinterpret_cast<F4*>(&ym[4 * i]) = ld4(p - SY - 3 + 4 * i);
        }
        // single-quad rows
        F4 x2p = ld4(p + 2 * SX), x2m = ld4(p - 2 * SX);
        F4 y2p = ld4(p + 2 * SY), y2m = ld4(p - 2 * SY);
        F4 pp = ld4(p + SX + SY), pm = ld4(p + SX - SY);
        F4 mp = ld4(p - SX + SY), mm = ld4(p - SX - SY);

#pragma unroll
        for (int j = 0; j < 4; ++j) {
            float ctr = c[j + 6];
            float dxx = 0.25f * (x2p[j] - 2.0f * ctr + x2m[j]);
            float dyy = 0.25f * (y2p[j] - 2.0f * ctr + y2m[j]);
            float dzz = 0.25f * (c[j + 12] - 2.0f * ctr + c[j]);
            float dxy = 0.25f * (pp[j] - mp[j] - pm[j] + mm[j]);
            float dxz = 0.25f * (xp[j + 6] - xm[j + 6] - xp[j] + xm[j]);
            float dyz = 0.25f * (yp[j + 6] - ym[j + 6] - yp[j] + ym[j]);
            e += dxx * dxx + dyy * dyy + dzz * dzz
               + 2.0f * (dxy * dxy + dxz * dxz + dyz * dyz);
        }
    }

    // wave-64 reduction -> block reduction -> one atomic per block
#pragma unroll
    for (int off = 32; off > 0; off >>= 1) e += __shfl_down(e, off, 64);

    __shared__ float ws[4];
    int lane = threadIdx.x & 63;
    int wid = threadIdx.x >> 6;
    if (lane == 0) ws[wid] = e;
    __syncthreads();
    if (threadIdx.x == 0) {
        float s = ws[0] + ws[1] + ws[2] + ws[3];
        const float inv_count = 1.0f / (156.0f * 156.0f * 156.0f * 3.0f);
        atomicAdd(&out[(blockIdx.x % NXCD) * CPX + blockIdx.x / NXCD >= 0
                           ? ((blockIdx.x % NXCD) * CPX + blockIdx.x / NXCD) / B1
                           : 0],
                  s * inv_count);
    }
}

extern "C" void kernel_launch(void* const* d_in, const int* in_sizes, int n_in,
                              void* d_out, int out_size, void* d_ws, size_t ws_size,
                              hipStream_t stream) {
    const float* f = (const float*)d_in[0];
    float* out = (float*)d_out;

    hipMemsetAsync(d_out, 0, out_size * sizeof(float), stream);

    dim3 block(256);
    dim3 grid(NWG);
    bending_energy_kernel<<<grid, block, 0, stream>>>(f, out);
}

// Round 4
// 209.597 us; speedup vs baseline: 10.8483x; 2.7728x over previous
//
#include <hip/hip_runtime.h>

// BendingEnergy: fused 19-point stencil + per-batch mean reduction.
// f: (4, 160, 160, 160, 3) f32, m = z*3+c fused contiguous axis (480/row).
// One thread = 12 consecutive m-outputs at m0 = 12*tq (16B-aligned!), 51
// aligned float4 loads issued back-to-back (sched_barrier pins them before
// compute -> full MLP), then fully unrolled stencil. Edge tiles masked.
// 1D grid ordered (tq, y, x, b) + bijective XCD chunking for L2 locality.

#define DIM 160
#define NOUT 156
#define SX (160 * 160 * 3)
#define SY (160 * 3)
#define NT 40                       // 12-wide m-tiles per (x,y) row
#define NPT (156 * 156 * 40)        // threads per batch = 973440
#define B1 3804                     // blocks per batch (NWG % 8 == 0)
#define NWG (4 * B1)                // 15216
#define CPX (NWG / 8)               // 1902

typedef float F4 __attribute__((ext_vector_type(4)));

__device__ __forceinline__ F4 ld4(const float* p) {
    return *reinterpret_cast<const F4*>(p);
}

__global__ __launch_bounds__(256, 1) void bending_energy_kernel(
    const float* __restrict__ f, float* __restrict__ out) {
    int bid = blockIdx.x;
    int sid = (bid & 7) * CPX + (bid >> 3);   // bijective XCD chunking
    int b = sid / B1;
    int n = (sid % B1) * 256 + threadIdx.x;

    float e = 0.0f;
    if (n < NPT) {
        int tq = n % NT;
        int r = n / NT;
        int y = r % NOUT + 2;
        int x = r / NOUT + 2;
        const float* p = f + (long long)b * (DIM * DIM * DIM * 3)
                           + (long long)x * SX + y * SY + 12 * tq;

        // ---- load phase: 51 aligned float4 loads, all independent ----
        float C[28];                  // center row, m0-8 .. m0+20
        float XP[20], XM[20], YP[20], YM[20];  // x+-1 / y+-1, m0-4 .. m0+16
        F4 X2P[3], X2M[3], Y2P[3], Y2M[3];     // x+-2 / y+-2, m0 .. m0+12
        F4 DPP[3], DPM[3], DMP[3], DMM[3];     // diagonals,   m0 .. m0+12
#pragma unroll
        for (int i = 0; i < 7; ++i)
            *reinterpret_cast<F4*>(&C[4 * i]) = ld4(p - 8 + 4 * i);
#pragma unroll
        for (int i = 0; i < 5; ++i) {
            *reinterpret_cast<F4*>(&XP[4 * i]) = ld4(p + SX - 4 + 4 * i);
            *reinterpret_cast<F4*>(&XM[4 * i]) = ld4(p - SX - 4 + 4 * i);
            *reinterpret_cast<F4*>(&YP[4 * i]) = ld4(p + SY - 4 + 4 * i);
            *reinterpret_cast<F4*>(&YM[4 * i]) = ld4(p - SY - 4 + 4 * i);
        }
#pragma unroll
        for (int i = 0; i < 3; ++i) {
            X2P[i] = ld4(p + 2 * SX + 4 * i);
            X2M[i] = ld4(p - 2 * SX + 4 * i);
            Y2P[i] = ld4(p + 2 * SY + 4 * i);
            Y2M[i] = ld4(p - 2 * SY + 4 * i);
            DPP[i] = ld4(p + SX + SY + 4 * i);
            DPM[i] = ld4(p + SX - SY + 4 * i);
            DMP[i] = ld4(p - SX + SY + 4 * i);
            DMM[i] = ld4(p - SX - SY + 4 * i);
        }
        __builtin_amdgcn_sched_barrier(0);  // pin: all loads issued first

        // ---- compute phase: 12 outputs, compile-time indices only ----
        int jlo = (tq == 0) ? 6 : 0;        // valid m range is [6, 474)
        int jhi = (tq == NT - 1) ? 6 : 12;
#pragma unroll
        for (int j = 0; j < 12; ++j) {
            float ctr = C[j + 8];
            float dxx = 0.25f * (X2P[j >> 2][j & 3] - 2.0f * ctr + X2M[j >> 2][j & 3]);
            float dyy = 0.25f * (Y2P[j >> 2][j & 3] - 2.0f * ctr + Y2M[j >> 2][j & 3]);
            float dzz = 0.25f * (C[j + 14] - 2.0f * ctr + C[j + 2]);
            float dxy = 0.25f * (DPP[j >> 2][j & 3] - DMP[j >> 2][j & 3]
                               - DPM[j >> 2][j & 3] + DMM[j >> 2][j & 3]);
            float dxz = 0.25f * (XP[j + 7] - XM[j + 7] - XP[j + 1] + XM[j + 1]);
            float dyz = 0.25f * (YP[j + 7] - YM[j + 7] - YP[j + 1] + YM[j + 1]);
            float mask = (j >= jlo && j < jhi) ? 1.0f : 0.0f;
            e += mask * (dxx * dxx + dyy * dyy + dzz * dzz
                       + 2.0f * (dxy * dxy + dxz * dxz + dyz * dyz));
        }
    }

    // wave-64 reduction -> block reduction -> one atomic per block
#pragma unroll
    for (int off = 32; off > 0; off >>= 1) e += __shfl_down(e, off, 64);

    __shared__ float ws[4];
    int lane = threadIdx.x & 63;
    int wid = threadIdx.x >> 6;
    if (lane == 0) ws[wid] = e;
    __syncthreads();
    if (threadIdx.x == 0) {
        float s = ws[0] + ws[1] + ws[2] + ws[3];
        const float inv_count = 1.0f / (156.0f * 156.0f * 156.0f * 3.0f);
        atomicAdd(&out[b], s * inv_count);
    }
}

extern "C" void kernel_launch(void* const* d_in, const int* in_sizes, int n_in,
                              void* d_out, int out_size, void* d_ws, size_t ws_size,
                              hipStream_t stream) {
    const float* f = (const float*)d_in[0];
    float* out = (float*)d_out;

    hipMemsetAsync(d_out, 0, out_size * sizeof(float), stream);

    dim3 block(256);
    dim3 grid(NWG);
    bending_energy_kernel<<<grid, block, 0, stream>>>(f, out);
}

// Round 5
// 167.267 us; speedup vs baseline: 13.5937x; 1.2531x over previous
//
#include <hip/hip_runtime.h>

// BendingEnergy: fused 19-point stencil + per-batch mean, LDS x-march version.
// f: (4, 160, 160, 160, 3) f32, m = z*3+c fused contiguous axis (480/row).
// Block(128) owns (y-tile=6, m-half) and marches 26 x-steps; 6-slot circular
// LDS buffer of x-slices (10 rows x 268 floats), staged with
// global_load_lds(16B). Compute: 21 m-threads x 6 y-rows, 12 outputs/thread,
// all ds_read_b128 16B-aligned. Stage(x+3) issued before compute(x) so HBM/L2
// latency hides under LDS reads. One barrier/step.

#define DIM 160
#define SX (DIM * DIM * 3)          // 76800
#define SY (DIM * 3)                // 480
#define FSZ ((long long)DIM * SX)   // floats per batch
#define TOT (4LL * FSZ)

#define YT 6                        // output y rows per block
#define NTH 21                      // m-threads per row (12-wide each)
#define NACT (YT * NTH)             // 126 active compute threads
#define SLOTS 6
#define ROWF 268                    // staged floats per row (stride, %4==0)
#define CHROW 67                    // 16B chunks per row
#define SLICE_CH 670                // chunks per slice (10 rows)
#define SLICE_F (SLICE_CH * 4)      // 2680 floats
#define STEPS 26                    // x steps per segment
#define NSEG 6
#define NYT 26
#define NBLK (NYT * 2 * NSEG * 4)   // 1248

typedef float F4 __attribute__((ext_vector_type(4)));

__global__ __launch_bounds__(128) void be_kernel(const float* __restrict__ f,
                                                 float* __restrict__ out) {
    __shared__ float lds[SLICE_F * SLOTS];   // 64320 B
    const int tid = threadIdx.x;

    // XCD-chunked bijective decode: 1248 = 8 * 156; same-XCD blocks share
    // one (b, x-segment) volume -> ~1.8 MB instantaneous L2 footprint.
    int lid = (blockIdx.x & 7) * (NBLK / 8) + (blockIdx.x >> 3);
    int p = lid / 52, q = lid % 52;          // p: (b,seg) pair, q: (h,yt)
    int b = p / NSEG, seg = p % NSEG;
    int h = q / NYT, yt = q % NYT;

    const int X0 = 2 + seg * STEPS;
    const int Y0 = 2 + yt * YT;
    const int gy0 = Y0 - 2;                  // first staged global y row
    const int Gm = h * 240 - 12;             // first staged m (float units)
    const long long bb = (long long)b * FSZ;
    const float* fend = f + (TOT - 4);

    // compute-thread roles
    int t = tid % NTH;                       // m-tile within row
    int yy = tid / NTH;                      // y row within tile
    bool active = (tid < NACT);
    if (!active) { t = 0; yy = 0; }
    const int m0 = h * 240 + 12 * t - 4;
    const int Mlo = h ? 240 : 6;
    const int Mhi = h ? 474 : 240;
    int jlo = Mlo - m0; if (jlo < 0) jlo = 0;
    int jhi = Mhi - m0; if (jhi > 12) jhi = 12;
    if (!active) jhi = -1;

    __attribute__((address_space(3))) float* lds3 =
        (__attribute__((address_space(3))) float*)lds;

    // ---- staging: one x-slab (10 rows x 268 floats) into a slice slot ----
    auto stage = [&](int slab) {
        int slot = slab % SLOTS;
        __attribute__((address_space(3))) float* lb = lds3 + slot * SLICE_F;
        long long base = bb + (long long)slab * SX + Gm;
#pragma unroll
        for (int it = 0; it < 6; ++it) {
            int c = it * 128 + tid;
            if (c < SLICE_CH) {
                int row = c / CHROW;
                int col = c - row * CHROW;
                const float* gp = f + (base + (long long)(gy0 + row) * SY + 4 * col);
                gp = gp < f ? f : gp;        // clamp buffer ends (garbage-safe)
                gp = gp > fend ? fend : gp;
                __builtin_amdgcn_global_load_lds(
                    (const __attribute__((address_space(1))) unsigned int*)gp,
                    (__attribute__((address_space(3))) unsigned int*)(lb + 4 * c),
                    16, 0, 0);
            }
        }
    };

    // prologue: slices X0-2 .. X0+2
    for (int d = -2; d <= 2; ++d) stage(X0 + d);
    __syncthreads();

    const int rc = (yy + 2) * ROWF + 12 * t;

    float e = 0.0f;
    for (int s = 0; s < STEPS; ++s) {
        int x = X0 + s;
        stage(x + 3);                        // prefetch; lands by the barrier

        int B0  = (x % SLOTS) * SLICE_F;
        int Bp1 = ((x + 1) % SLOTS) * SLICE_F;
        int Bm1 = ((x + 5) % SLOTS) * SLICE_F;
        int Bp2 = ((x + 2) % SLOTS) * SLICE_F;
        int Bm2 = ((x + 4) % SLOTS) * SLICE_F;

        const float* L = lds;
        float C[28];
        float XP[20], XM[20], YP[20], YM[20];
        F4 X2P[3], X2M[3], Y2P[3], Y2M[3];
        F4 DPP[3], DPM[3], DMP[3], DMM[3];
#pragma unroll
        for (int i = 0; i < 7; ++i)
            *reinterpret_cast<F4*>(&C[4 * i]) =
                *reinterpret_cast<const F4*>(&L[B0 + rc + 4 * i]);
#pragma unroll
        for (int i = 0; i < 5; ++i) {
            *reinterpret_cast<F4*>(&XP[4 * i]) =
                *reinterpret_cast<const F4*>(&L[Bp1 + rc + 4 + 4 * i]);
            *reinterpret_cast<F4*>(&XM[4 * i]) =
                *reinterpret_cast<const F4*>(&L[Bm1 + rc + 4 + 4 * i]);
            *reinterpret_cast<F4*>(&YP[4 * i]) =
                *reinterpret_cast<const F4*>(&L[B0 + rc + ROWF + 4 + 4 * i]);
            *reinterpret_cast<F4*>(&YM[4 * i]) =
                *reinterpret_cast<const F4*>(&L[B0 + rc - ROWF + 4 + 4 * i]);
        }
#pragma unroll
        for (int i = 0; i < 3; ++i) {
            X2P[i] = *reinterpret_cast<const F4*>(&L[Bp2 + rc + 8 + 4 * i]);
            X2M[i] = *reinterpret_cast<const F4*>(&L[Bm2 + rc + 8 + 4 * i]);
            Y2P[i] = *reinterpret_cast<const F4*>(&L[B0 + rc + 2 * ROWF + 8 + 4 * i]);
            Y2M[i] = *reinterpret_cast<const F4*>(&L[B0 + rc - 2 * ROWF + 8 + 4 * i]);
            DPP[i] = *reinterpret_cast<const F4*>(&L[Bp1 + rc + ROWF + 8 + 4 * i]);
            DPM[i] = *reinterpret_cast<const F4*>(&L[Bp1 + rc - ROWF + 8 + 4 * i]);
            DMP[i] = *reinterpret_cast<const F4*>(&L[Bm1 + rc + ROWF + 8 + 4 * i]);
            DMM[i] = *reinterpret_cast<const F4*>(&L[Bm1 + rc - ROWF + 8 + 4 * i]);
        }

#pragma unroll
        for (int j = 0; j < 12; ++j) {
            float ctr = C[j + 8];
            float dxx = 0.25f * (X2P[j >> 2][j & 3] - 2.0f * ctr + X2M[j >> 2][j & 3]);
            float dyy = 0.25f * (Y2P[j >> 2][j & 3] - 2.0f * ctr + Y2M[j >> 2][j & 3]);
            float dzz = 0.25f * (C[j + 14] - 2.0f * ctr + C[j + 2]);
            float dxy = 0.25f * (DPP[j >> 2][j & 3] - DMP[j >> 2][j & 3]
                               - DPM[j >> 2][j & 3] + DMM[j >> 2][j & 3]);
            float dxz = 0.25f * (XP[j + 7] - XM[j + 7] - XP[j + 1] + XM[j + 1]);
            float dyz = 0.25f * (YP[j + 7] - YM[j + 7] - YP[j + 1] + YM[j + 1]);
            float mask = (j >= jlo && j < jhi) ? 1.0f : 0.0f;
            e += mask * (dxx * dxx + dyy * dyy + dzz * dzz
                       + 2.0f * (dxy * dxy + dxz * dxz + dyz * dyz));
        }

        __syncthreads();   // drains stage(x+3) vmcnt + orders slot reuse
    }

    // block reduction (2 waves) -> one atomic per block
#pragma unroll
    for (int off = 32; off > 0; off >>= 1) e += __shfl_down(e, off, 64);

    __shared__ float ws[2];
    int lane = tid & 63;
    int wid = tid >> 6;
    if (lane == 0) ws[wid] = e;
    __syncthreads();
    if (tid == 0) {
        const float inv_count = 1.0f / (156.0f * 156.0f * 156.0f * 3.0f);
        atomicAdd(&out[b], (ws[0] + ws[1]) * inv_count);
    }
}

extern "C" void kernel_launch(void* const* d_in, const int* in_sizes, int n_in,
                              void* d_out, int out_size, void* d_ws, size_t ws_size,
                              hipStream_t stream) {
    const float* f = (const float*)d_in[0];
    float* out = (float*)d_out;

    hipMemsetAsync(d_out, 0, out_size * sizeof(float), stream);

    be_kernel<<<dim3(NBLK), dim3(128), 0, stream>>>(f, out);
}

// Round 6
// 153.133 us; speedup vs baseline: 14.8484x; 1.0923x over previous
//
#include <hip/hip_runtime.h>

// BendingEnergy: fused 19-point stencil + per-batch mean, LDS x-march v2.
// f: (4, 160, 160, 160, 3) f32, m = z*3+c fused contiguous axis (480/row).
// Block(128) = 16 y-rows x 8 m-tiles (8-wide). 6-slot circular LDS buffer of
// x-slabs (20 rows x 88 floats, padded to 448 16B-units/slice). LDS layout is
// XOR-swizzled (u ^ ((u>>3)&7), an involution) to kill ds_read bank
// conflicts; applied on the global SOURCE of global_load_lds (dest stays
// linear, as HW requires) and on the precomputed read offsets.

typedef float F4 __attribute__((ext_vector_type(4)));

#define DIM 160
#define SX (DIM * DIM * 3)          // 76800
#define SY (DIM * 3)                // 480
#define FSZ ((long long)DIM * SX)
#define TOT (4LL * FSZ)

#define ROWS 20                     // staged y rows per slab (16 out + 4 halo)
#define ROWU 22                     // 16B units per staged row (88 floats)
#define USED_U (ROWS * ROWU)        // 440
#define SLICE_U 448                 // padded (mult of 8 -> slot-invariant swz)
#define SLICE_F (SLICE_U * 4)       // 1792 floats
#define SLOTS 6
#define STEPS 26
#define NSEG 6                      // x segments
#define NMS 8                       // m segments (64-wide cores)
#define NYT 10                      // y tiles (16-wide)
#define NBLK (4 * NSEG * NMS * NYT) // 1920
#define CPX (NBLK / 8)

__device__ __forceinline__ int swz(int u) { return u ^ ((u >> 3) & 7); }

__global__ __launch_bounds__(128) void be_kernel(const float* __restrict__ f,
                                                 float* __restrict__ out) {
    __shared__ float lds[SLICE_F * SLOTS];   // 43008 B
    const int tid = threadIdx.x;

    // bijective XCD chunking; same-XCD blocks share (b, xseg) slab volumes
    int lid = (blockIdx.x & 7) * CPX + (blockIdx.x >> 3);
    int p2 = lid / (NMS * NYT);
    int q2 = lid % (NMS * NYT);
    int b = p2 / NSEG, xseg = p2 % NSEG;
    int ms = q2 / NYT, yt = q2 % NYT;

    const int X0 = 2 + xseg * STEPS;
    const int gy0 = 16 * yt;                 // first staged global y row
    const int core = 4 + 64 * ms;            // first output m of this segment
    const int Gm = core - 8;                 // staged m start (16B-aligned)
    const long long bb = (long long)b * FSZ;
    const float* fend = f + (TOT - 4);

    const int t = tid & 7;                   // m-tile
    const int yy = tid >> 3;                 // y row within tile
    const int m0 = core + 8 * t;
    const int y = 2 + 16 * yt + yy;

    int jlo = 6 - m0; if (jlo < 0) jlo = 0;  // valid m in [6, 474)
    int jhi = 474 - m0; if (jhi > 8) jhi = 8;
    if (y >= DIM - 2) jhi = -1;              // y edge mask

    // precomputed swizzled unit offsets (slot-invariant)
    int pR[6], pYp[4], pYm[4], pY2p[2], pY2m[2];
#pragma unroll
    for (int du = 0; du < 6; ++du) pR[du] = swz((yy + 2) * ROWU + 2 * t + du);
#pragma unroll
    for (int du = 0; du < 4; ++du) {
        pYp[du] = swz((yy + 3) * ROWU + 2 * t + du + 1);
        pYm[du] = swz((yy + 1) * ROWU + 2 * t + du + 1);
    }
#pragma unroll
    for (int du = 0; du < 2; ++du) {
        pY2p[du] = swz((yy + 4) * ROWU + 2 * t + du + 2);
        pY2m[du] = swz((yy + 0) * ROWU + 2 * t + du + 2);
    }

    auto stage = [&](int slab) {
        int slot = slab % SLOTS;
#pragma unroll
        for (int it = 0; it < 4; ++it) {
            int c = it * 128 + tid;          // linear LDS dest unit
            if (c < USED_U) {
                int l = swz(c);              // logical unit this slot holds
                int row = l / ROWU;
                int col = l - row * ROWU;
                const float* gp = f + (bb + (long long)slab * SX
                                       + (long long)(gy0 + row) * SY
                                       + Gm + 4 * col);
                gp = gp < f ? f : gp;        // clamp (garbage-safe, masked)
                gp = gp > fend ? fend : gp;
                __builtin_amdgcn_global_load_lds(
                    (const __attribute__((address_space(1))) unsigned int*)gp,
                    (__attribute__((address_space(3))) unsigned int*)
                        ((__attribute__((address_space(3))) float*)lds
                         + slot * SLICE_F + 4 * c),
                    16, 0, 0);
            }
        }
    };

    for (int d = -2; d <= 2; ++d) stage(X0 + d);
    __syncthreads();

    float e = 0.0f;
    for (int s = 0; s < STEPS; ++s) {
        int x = X0 + s;
        stage(x + 3);                        // into slot of x-3: no race

        int B0  = (x % SLOTS) * SLICE_F;
        int Bp1 = ((x + 1) % SLOTS) * SLICE_F;
        int Bm1 = ((x + 5) % SLOTS) * SLICE_F;
        int Bp2 = ((x + 2) % SLOTS) * SLICE_F;
        int Bm2 = ((x + 4) % SLOTS) * SLICE_F;

        float C[24], XP[16], XM[16], YP[16], YM[16];
        F4 X2P[2], X2M[2], Y2P[2], Y2M[2], DPP[2], DPM[2], DMP[2], DMM[2];
#pragma unroll
        for (int i = 0; i < 6; ++i)
            *reinterpret_cast<F4*>(&C[4 * i]) =
                *reinterpret_cast<const F4*>(&lds[B0 + 4 * pR[i]]);
#pragma unroll
        for (int i = 0; i < 4; ++i) {
            *reinterpret_cast<F4*>(&XP[4 * i]) =
                *reinterpret_cast<const F4*>(&lds[Bp1 + 4 * pR[i + 1]]);
            *reinterpret_cast<F4*>(&XM[4 * i]) =
                *reinterpret_cast<const F4*>(&lds[Bm1 + 4 * pR[i + 1]]);
            *reinterpret_cast<F4*>(&YP[4 * i]) =
                *reinterpret_cast<const F4*>(&lds[B0 + 4 * pYp[i]]);
            *reinterpret_cast<F4*>(&YM[4 * i]) =
                *reinterpret_cast<const F4*>(&lds[B0 + 4 * pYm[i]]);
        }
#pragma unroll
        for (int i = 0; i < 2; ++i) {
            X2P[i] = *reinterpret_cast<const F4*>(&lds[Bp2 + 4 * pR[i + 2]]);
            X2M[i] = *reinterpret_cast<const F4*>(&lds[Bm2 + 4 * pR[i + 2]]);
            Y2P[i] = *reinterpret_cast<const F4*>(&lds[B0 + 4 * pY2p[i]]);
            Y2M[i] = *reinterpret_cast<const F4*>(&lds[B0 + 4 * pY2m[i]]);
            DPP[i] = *reinterpret_cast<const F4*>(&lds[Bp1 + 4 * pYp[i + 1]]);
            DPM[i] = *reinterpret_cast<const F4*>(&lds[Bp1 + 4 * pYm[i + 1]]);
            DMP[i] = *reinterpret_cast<const F4*>(&lds[Bm1 + 4 * pYp[i + 1]]);
            DMM[i] = *reinterpret_cast<const F4*>(&lds[Bm1 + 4 * pYm[i + 1]]);
        }

#pragma unroll
        for (int j = 0; j < 8; ++j) {
            float ctr = C[j + 8];
            float dxx = 0.25f * (X2P[j >> 2][j & 3] - 2.0f * ctr + X2M[j >> 2][j & 3]);
            float dyy = 0.25f * (Y2P[j >> 2][j & 3] - 2.0f * ctr + Y2M[j >> 2][j & 3]);
            float dzz = 0.25f * (C[j + 14] - 2.0f * ctr + C[j + 2]);
            float dxy = 0.25f * (DPP[j >> 2][j & 3] - DMP[j >> 2][j & 3]
                               - DPM[j >> 2][j & 3] + DMM[j >> 2][j & 3]);
            float dxz = 0.25f * (XP[j + 7] - XM[j + 7] - XP[j + 1] + XM[j + 1]);
            float dyz = 0.25f * (YP[j + 7] - YM[j + 7] - YP[j + 1] + YM[j + 1]);
            float msk = (j >= jlo && j < jhi) ? 1.0f : 0.0f;
            e += msk * (dxx * dxx + dyy * dyy + dzz * dzz
                      + 2.0f * (dxy * dxy + dxz * dxz + dyz * dyz));
        }

        __syncthreads();   // drains stage vmcnt + orders slot reuse
    }

    // wave reduce -> block reduce -> one atomic per block
#pragma unroll
    for (int off = 32; off > 0; off >>= 1) e += __shfl_down(e, off, 64);

    __shared__ float ws[2];
    int lane = tid & 63;
    int wid = tid >> 6;
    if (lane == 0) ws[wid] = e;
    __syncthreads();
    if (tid == 0) {
        const float inv_count = 1.0f / (156.0f * 156.0f * 156.0f * 3.0f);
        atomicAdd(&out[b], (ws[0] + ws[1]) * inv_count);
    }
}

extern "C" void kernel_launch(void* const* d_in, const int* in_sizes, int n_in,
                              void* d_out, int out_size, void* d_ws, size_t ws_size,
                              hipStream_t stream) {
    const float* f = (const float*)d_in[0];
    float* out = (float*)d_out;

    hipMemsetAsync(d_out, 0, out_size * sizeof(float), stream);

    be_kernel<<<dim3(NBLK), dim3(128), 0, stream>>>(f, out);
}

// Round 7
// 136.157 us; speedup vs baseline: 16.6997x; 1.1247x over previous
//
#include <hip/hip_runtime.h>

// BendingEnergy: fused 19-point stencil + per-batch mean, LDS x-march v3.
// f: (4, 160, 160, 160, 3) f32, m = z*3+c fused contiguous axis (480/row).
// Block(128) = 16 y-rows (yy = tid&15, lane-major!) x 8 m-tiles (t = tid>>4,
// 8-wide). 6-slot circular LDS buffer of x-slabs: 20 rows x 23 16B-units,
// ODD row stride -> residue (unit mod 8) steps by 7 per row -> each 8-lane
// phase of a ds_read_b128 hits all 8 bank-quads exactly once. No swizzle;
// stage is linear global_load_lds(16B); reads are base + imm offsets.

typedef float F4 __attribute__((ext_vector_type(4)));

#define DIM 160
#define SX (DIM * DIM * 3)          // 76800
#define SY (DIM * 3)                // 480
#define FSZ ((long long)DIM * SX)
#define TOT (4LL * FSZ)

#define ROWS 20                     // staged y rows per slab (16 out + 4 halo)
#define ROWU 23                     // 16B units per row (22 used + 1 pad), ODD
#define USED_U (ROWS * ROWU)        // 460
#define SLICE_U 464                 // padded to mult of 8 (slot-invariant)
#define SLICE_F (SLICE_U * 4)       // 1856 floats
#define SLOTS 6
#define STEPS 26
#define NSEG 6                      // x segments
#define NMS 8                       // m segments (64 output floats each)
#define NYT 10                      // y tiles (16 rows each)
#define NBLK (4 * NSEG * NMS * NYT) // 1920
#define CPX (NBLK / 8)

__global__ __launch_bounds__(128) void be_kernel(const float* __restrict__ f,
                                                 float* __restrict__ out) {
    __shared__ float lds[SLICE_F * SLOTS];   // 44544 B
    const int tid = threadIdx.x;

    // bijective XCD chunking; same-XCD blocks share (b, xseg) slab volumes
    int lid = (blockIdx.x & 7) * CPX + (blockIdx.x >> 3);
    int p2 = lid / (NMS * NYT);
    int q2 = lid % (NMS * NYT);
    int b = p2 / NSEG, xseg = p2 % NSEG;
    int ms = q2 / NYT, yt = q2 % NYT;

    const int X0 = 2 + xseg * STEPS;
    const int gy0 = 16 * yt;                 // first staged global y row
    const int core = 4 + 64 * ms;            // first output m of this segment
    const int Gm = core - 8;                 // staged m start (16B-aligned)
    const long long bb = (long long)b * FSZ;
    const float* fend = f + (TOT - 4);

    const int t = tid >> 4;                  // m-tile (wave0: 0..3, wave1: 4..7)
    const int yy = tid & 15;                 // y row within tile, lane-major
    const int m0 = core + 8 * t;
    const int y = 2 + 16 * yt + yy;

    int jlo = 6 - m0; if (jlo < 0) jlo = 0;  // valid m in [6, 474)
    int jhi = 474 - m0; if (jhi > 8) jhi = 8;
    if (y >= DIM - 2) jhi = -1;              // y edge mask

    // unit of (center row, m0-8); all reads are this + compile-time offsets
    const int rc = (yy + 2) * ROWU + 2 * t;

    auto stage = [&](int slab) {
        int slot = slab % SLOTS;
        long long gbase = bb + (long long)slab * SX + Gm;
#pragma unroll
        for (int it = 0; it < 4; ++it) {
            int c = it * 128 + tid;          // linear LDS dest unit
            if (c < USED_U) {
                int row = c / ROWU;
                int col = c - row * ROWU;    // col 22 = pad (garbage, unread)
                const float* gp = f + (gbase + (long long)(gy0 + row) * SY + 4 * col);
                gp = gp < f ? f : gp;        // clamp buffer ends (masked data)
                gp = gp > fend ? fend : gp;
                __builtin_amdgcn_global_load_lds(
                    (const __attribute__((address_space(1))) unsigned int*)gp,
                    (__attribute__((address_space(3))) unsigned int*)
                        ((__attribute__((address_space(3))) float*)lds
                         + slot * SLICE_F + 4 * c),
                    16, 0, 0);
            }
        }
    };

    for (int d = -2; d <= 2; ++d) stage(X0 + d);
    __syncthreads();

    float e = 0.0f;
    for (int s = 0; s < STEPS; ++s) {
        int x = X0 + s;
        stage(x + 3);                        // into slot of slab x-3: no race

        const float* L0  = lds + ((x    ) % SLOTS) * SLICE_F + 4 * rc;
        const float* Lp1 = lds + ((x + 1) % SLOTS) * SLICE_F + 4 * rc;
        const float* Lm1 = lds + ((x + 5) % SLOTS) * SLICE_F + 4 * rc;
        const float* Lp2 = lds + ((x + 2) % SLOTS) * SLICE_F + 4 * rc;
        const float* Lm2 = lds + ((x + 4) % SLOTS) * SLICE_F + 4 * rc;

        float C[24], XP[16], XM[16], YP[16], YM[16];
        F4 X2P[2], X2M[2], Y2P[2], Y2M[2], DPP[2], DPM[2], DMP[2], DMM[2];
        // C: units rc+0..5 (floats m0-8 .. m0+15)
#pragma unroll
        for (int i = 0; i < 6; ++i)
            *reinterpret_cast<F4*>(&C[4 * i]) =
                *reinterpret_cast<const F4*>(L0 + 4 * i);
        // x+-1 / y+-1 rows: 4 units each (floats m0-4 .. m0+11)
#pragma unroll
        for (int i = 0; i < 4; ++i) {
            *reinterpret_cast<F4*>(&XP[4 * i]) =
                *reinterpret_cast<const F4*>(Lp1 + 4 + 4 * i);
            *reinterpret_cast<F4*>(&XM[4 * i]) =
                *reinterpret_cast<const F4*>(Lm1 + 4 + 4 * i);
            *reinterpret_cast<F4*>(&YP[4 * i]) =
                *reinterpret_cast<const F4*>(L0 + 4 * ROWU + 4 + 4 * i);
            *reinterpret_cast<F4*>(&YM[4 * i]) =
                *reinterpret_cast<const F4*>(L0 - 4 * ROWU + 4 + 4 * i);
        }
        // quads: 2 units each (floats m0 .. m0+7)
#pragma unroll
        for (int i = 0; i < 2; ++i) {
            X2P[i] = *reinterpret_cast<const F4*>(Lp2 + 8 + 4 * i);
            X2M[i] = *reinterpret_cast<const F4*>(Lm2 + 8 + 4 * i);
            Y2P[i] = *reinterpret_cast<const F4*>(L0 + 8 * ROWU + 8 + 4 * i);
            Y2M[i] = *reinterpret_cast<const F4*>(L0 - 8 * ROWU + 8 + 4 * i);
            DPP[i] = *reinterpret_cast<const F4*>(Lp1 + 4 * ROWU + 8 + 4 * i);
            DPM[i] = *reinterpret_cast<const F4*>(Lp1 - 4 * ROWU + 8 + 4 * i);
            DMP[i] = *reinterpret_cast<const F4*>(Lm1 + 4 * ROWU + 8 + 4 * i);
            DMM[i] = *reinterpret_cast<const F4*>(Lm1 - 4 * ROWU + 8 + 4 * i);
        }

#pragma unroll
        for (int j = 0; j < 8; ++j) {
            float ctr = C[j + 8];
            float dxx = 0.25f * (X2P[j >> 2][j & 3] - 2.0f * ctr + X2M[j >> 2][j & 3]);
            float dyy = 0.25f * (Y2P[j >> 2][j & 3] - 2.0f * ctr + Y2M[j >> 2][j & 3]);
            float dzz = 0.25f * (C[j + 14] - 2.0f * ctr + C[j + 2]);
            float dxy = 0.25f * (DPP[j >> 2][j & 3] - DMP[j >> 2][j & 3]
                               - DPM[j >> 2][j & 3] + DMM[j >> 2][j & 3]);
            float dxz = 0.25f * (XP[j + 7] - XM[j + 7] - XP[j + 1] + XM[j + 1]);
            float dyz = 0.25f * (YP[j + 7] - YM[j + 7] - YP[j + 1] + YM[j + 1]);
            float msk = (j >= jlo && j < jhi) ? 1.0f : 0.0f;
            e += msk * (dxx * dxx + dyy * dyy + dzz * dzz
                      + 2.0f * (dxy * dxy + dxz * dxz + dyz * dyz));
        }

        __syncthreads();   // drains stage vmcnt + orders slot reuse
    }

    // wave reduce -> block reduce -> one atomic per block
#pragma unroll
    for (int off = 32; off > 0; off >>= 1) e += __shfl_down(e, off, 64);

    __shared__ float ws[2];
    int lane = tid & 63;
    int wid = tid >> 6;
    if (lane == 0) ws[wid] = e;
    __syncthreads();
    if (tid == 0) {
        const float inv_count = 1.0f / (156.0f * 156.0f * 156.0f * 3.0f);
        atomicAdd(&out[b], (ws[0] + ws[1]) * inv_count);
    }
}

extern "C" void kernel_launch(void* const* d_in, const int* in_sizes, int n_in,
                              void* d_out, int out_size, void* d_ws, size_t ws_size,
                              hipStream_t stream) {
    const float* f = (const float*)d_in[0];
    float* out = (float*)d_out;

    hipMemsetAsync(d_out, 0, out_size * sizeof(float), stream);

    be_kernel<<<dim3(NBLK), dim3(128), 0, stream>>>(f, out);
}

// Round 8
// 98.674 us; speedup vs baseline: 23.0433x; 1.3799x over previous
//
#include <hip/hip_runtime.h>

// BendingEnergy: fused 19-point stencil + per-batch mean, LDS x-march v4.
// f: (4, 160, 160, 160, 3) f32, m = z*3+c fused contiguous axis (480/row).
// Block(256) = 16 y-rows (yy = tid&15) x 16 m-tiles (t = tid>>4, 8-wide).
// 6-slot circular LDS buffer of x-slabs: 20 rows x 37 16B-units (odd row
// stride -> consecutive-8-lane phases hit all 8 bank-quads). 71.4 KB LDS ->
// 2 blocks/CU = 8 waves/CU. Stage is linear global_load_lds(16B); reads are
// base + compile-time imm. Raw 2nd differences; 0.0625 folded at the end.

typedef float F4 __attribute__((ext_vector_type(4)));

#define DIM 160
#define SX (DIM * DIM * 3)          // 76800
#define SY (DIM * 3)                // 480
#define FSZ ((long long)DIM * SX)
#define TOT (4LL * FSZ)

#define ROWS 20                     // staged y rows per slab (16 out + 4 halo)
#define ROWU 37                     // 16B units per row (36 used + 1 pad), ODD
#define USED_U (ROWS * ROWU)        // 740
#define SLICE_U 744                 // padded to mult of 8
#define SLICE_F (SLICE_U * 4)       // 2976 floats
#define SLOTS 6
#define STEPS 26
#define NSEG 6                      // x segments
#define NMS 4                       // m segments (128 output floats each)
#define NYT 10                      // y tiles (16 rows each)
#define NBLK (4 * NSEG * NMS * NYT) // 960
#define CPX (NBLK / 8)              // 120

__global__ __launch_bounds__(256, 2) void be_kernel(const float* __restrict__ f,
                                                    float* __restrict__ out) {
    __shared__ float lds[SLICE_F * SLOTS];   // 71424 B
    const int tid = threadIdx.x;

    // bijective XCD chunking; same-XCD blocks share (b, xseg) slab volumes
    int lid = (blockIdx.x & 7) * CPX + (blockIdx.x >> 3);
    int p2 = lid / (NMS * NYT);
    int q2 = lid % (NMS * NYT);
    int b = p2 / NSEG, xseg = p2 % NSEG;
    int ms = q2 / NYT, yt = q2 % NYT;

    const int X0 = 2 + xseg * STEPS;
    const int gy0 = 16 * yt;                 // first staged global y row
    const int core = 4 + 128 * ms;           // first output m of this segment
    const int Gm = core - 8;                 // staged m start (16B-aligned)
    const long long bb = (long long)b * FSZ;
    const float* fend = f + (TOT - 4);

    const int t = tid >> 4;                  // m-tile 0..15
    const int yy = tid & 15;                 // y row within tile (lane-fast)
    const int m0 = core + 8 * t;
    const int y = 2 + 16 * yt + yy;

    int jlo = 6 - m0; if (jlo < 0) jlo = 0;  // valid m in [6, 474)
    int jhi = 474 - m0; if (jhi > 8) jhi = 8;
    if (y >= DIM - 2) jhi = -1;              // y edge mask

    // unit of (center row, m0-8); all reads are this + compile-time offsets
    const int rc = (yy + 2) * ROWU + 2 * t;

    auto stage = [&](int slab) {
        int slot = slab % SLOTS;
        long long gbase = bb + (long long)slab * SX + Gm;
#pragma unroll
        for (int it = 0; it < 3; ++it) {
            int c = it * 256 + tid;          // linear LDS dest unit
            if (c < USED_U) {
                int row = c / ROWU;
                int col = c - row * ROWU;    // col 36 = pad (garbage, unread)
                const float* gp = f + (gbase + (long long)(gy0 + row) * SY + 4 * col);
                gp = gp < f ? f : gp;        // clamp buffer ends (masked data)
                gp = gp > fend ? fend : gp;
                __builtin_amdgcn_global_load_lds(
                    (const __attribute__((address_space(1))) unsigned int*)gp,
                    (__attribute__((address_space(3))) unsigned int*)
                        ((__attribute__((address_space(3))) float*)lds
                         + slot * SLICE_F + 4 * c),
                    16, 0, 0);
            }
        }
    };

    for (int d = -2; d <= 2; ++d) stage(X0 + d);
    __syncthreads();

    float e = 0.0f;                          // raw energy (x16 scale)
    for (int s = 0; s < STEPS; ++s) {
        int x = X0 + s;
        stage(x + 3);                        // into slot of slab x-3: no race

        const float* L0  = lds + ((x    ) % SLOTS) * SLICE_F + 4 * rc;
        const float* Lp1 = lds + ((x + 1) % SLOTS) * SLICE_F + 4 * rc;
        const float* Lm1 = lds + ((x + 5) % SLOTS) * SLICE_F + 4 * rc;
        const float* Lp2 = lds + ((x + 2) % SLOTS) * SLICE_F + 4 * rc;
        const float* Lm2 = lds + ((x + 4) % SLOTS) * SLICE_F + 4 * rc;

        float C[24], XP[16], XM[16], YP[16], YM[16];
        F4 X2P[2], X2M[2], Y2P[2], Y2M[2], DPP[2], DPM[2], DMP[2], DMM[2];
        // C: units rc+0..5 (floats m0-8 .. m0+15)
#pragma unroll
        for (int i = 0; i < 6; ++i)
            *reinterpret_cast<F4*>(&C[4 * i]) =
                *reinterpret_cast<const F4*>(L0 + 4 * i);
        // x+-1 / y+-1 rows: 4 units each (floats m0-4 .. m0+11)
#pragma unroll
        for (int i = 0; i < 4; ++i) {
            *reinterpret_cast<F4*>(&XP[4 * i]) =
                *reinterpret_cast<const F4*>(Lp1 + 4 + 4 * i);
            *reinterpret_cast<F4*>(&XM[4 * i]) =
                *reinterpret_cast<const F4*>(Lm1 + 4 + 4 * i);
            *reinterpret_cast<F4*>(&YP[4 * i]) =
                *reinterpret_cast<const F4*>(L0 + 4 * ROWU + 4 + 4 * i);
            *reinterpret_cast<F4*>(&YM[4 * i]) =
                *reinterpret_cast<const F4*>(L0 - 4 * ROWU + 4 + 4 * i);
        }
        // quads: 2 units each (floats m0 .. m0+7)
#pragma unroll
        for (int i = 0; i < 2; ++i) {
            X2P[i] = *reinterpret_cast<const F4*>(Lp2 + 8 + 4 * i);
            X2M[i] = *reinterpret_cast<const F4*>(Lm2 + 8 + 4 * i);
            Y2P[i] = *reinterpret_cast<const F4*>(L0 + 8 * ROWU + 8 + 4 * i);
            Y2M[i] = *reinterpret_cast<const F4*>(L0 - 8 * ROWU + 8 + 4 * i);
            DPP[i] = *reinterpret_cast<const F4*>(Lp1 + 4 * ROWU + 8 + 4 * i);
            DPM[i] = *reinterpret_cast<const F4*>(Lp1 - 4 * ROWU + 8 + 4 * i);
            DMP[i] = *reinterpret_cast<const F4*>(Lm1 + 4 * ROWU + 8 + 4 * i);
            DMM[i] = *reinterpret_cast<const F4*>(Lm1 - 4 * ROWU + 8 + 4 * i);
        }

#pragma unroll
        for (int j = 0; j < 8; ++j) {
            float ctr2 = 2.0f * C[j + 8];
            float dxx = (X2P[j >> 2][j & 3] + X2M[j >> 2][j & 3]) - ctr2;
            float dyy = (Y2P[j >> 2][j & 3] + Y2M[j >> 2][j & 3]) - ctr2;
            float dzz = (C[j + 14] + C[j + 2]) - ctr2;
            float dxy = (DPP[j >> 2][j & 3] - DMP[j >> 2][j & 3])
                      - (DPM[j >> 2][j & 3] - DMM[j >> 2][j & 3]);
            float dxz = (XP[j + 7] - XM[j + 7]) - (XP[j + 1] - XM[j + 1]);
            float dyz = (YP[j + 7] - YM[j + 7]) - (YP[j + 1] - YM[j + 1]);
            float dd = dxx * dxx + dyy * dyy + dzz * dzz;
            float dc = dxy * dxy + dxz * dxz + dyz * dyz;
            float msk = (j >= jlo && j < jhi) ? 1.0f : 0.0f;
            e += msk * (dd + 2.0f * dc);
        }

        __syncthreads();   // drains stage vmcnt + orders slot reuse
    }

    // wave reduce -> block reduce -> one atomic per block
#pragma unroll
    for (int off = 32; off > 0; off >>= 1) e += __shfl_down(e, off, 64);

    __shared__ float ws[4];
    int lane = tid & 63;
    int wid = tid >> 6;
    if (lane == 0) ws[wid] = e;
    __syncthreads();
    if (tid == 0) {
        // 0.0625 = (0.25)^2 from the two central-difference factors
        const float inv_count = 0.0625f / (156.0f * 156.0f * 156.0f * 3.0f);
        atomicAdd(&out[b], (ws[0] + ws[1] + ws[2] + ws[3]) * inv_count);
    }
}

extern "C" void kernel_launch(void* const* d_in, const int* in_sizes, int n_in,
                              void* d_out, int out_size, void* d_ws, size_t ws_size,
                              hipStream_t stream) {
    const float* f = (const float*)d_in[0];
    float* out = (float*)d_out;

    hipMemsetAsync(d_out, 0, out_size * sizeof(float), stream);

    be_kernel<<<dim3(NBLK), dim3(256), 0, stream>>>(f, out);
}

// Round 9
// 86.964 us; speedup vs baseline: 26.1462x; 1.1347x over previous
//
#include <hip/hip_runtime.h>

// BendingEnergy: fused 19-point stencil + per-batch mean, LDS x-march v5.
// f: (4, 160, 160, 160, 3) f32, m = z*3+c fused contiguous axis (480/row).
// Block(256) = 16 y-rows x 16 m-tiles (8-wide). 6-slot circular LDS buffer of
// x-slabs: 20 rows x 37 16B-units. Lane remap (yy bit0 = tid bit3) makes
// bank-quad residues injective over stride-8 lane phases -> conflict-free
// ds_read_b128. x-1 taps (XM/DMP/DMM) are register-FIFO'd from the x+1 reads
// two steps earlier (ping-pong sets, unroll-2 -> pure renames): 38 -> 30
// LDS units per thread-step.

typedef float F4 __attribute__((ext_vector_type(4)));

#define DIM 160
#define SX (DIM * DIM * 3)          // 76800
#define SY (DIM * 3)                // 480
#define FSZ ((long long)DIM * SX)
#define TOT (4LL * FSZ)

#define ROWS 20                     // staged y rows per slab (16 out + 4 halo)
#define ROWU 37                     // 16B units per row (36 used + 1 pad), ODD
#define USED_U (ROWS * ROWU)        // 740
#define SLICE_U 744                 // padded to mult of 8
#define SLICE_F (SLICE_U * 4)       // 2976 floats
#define SLOTS 6
#define STEPS 26
#define NSEG 6                      // x segments
#define NMS 4                       // m segments (128 output floats each)
#define NYT 10                      // y tiles (16 rows each)
#define NBLK (4 * NSEG * NMS * NYT) // 960
#define CPX (NBLK / 8)              // 120

__global__ __launch_bounds__(256, 2) void be_kernel(const float* __restrict__ f,
                                                    float* __restrict__ out) {
    __shared__ float lds[SLICE_F * SLOTS];   // 71424 B
    const int tid = threadIdx.x;

    // bijective XCD chunking; same-XCD blocks share (b, xseg) slab volumes
    int lid = (blockIdx.x & 7) * CPX + (blockIdx.x >> 3);
    int p2 = lid / (NMS * NYT);
    int q2 = lid % (NMS * NYT);
    int b = p2 / NSEG, xseg = p2 % NSEG;
    int ms = q2 / NYT, yt = q2 % NYT;

    const int X0 = 2 + xseg * STEPS;
    const int gy0 = 16 * yt;                 // first staged global y row
    const int core = 4 + 128 * ms;           // first output m of this segment
    const int Gm = core - 8;                 // staged m start (16B-aligned)
    const long long bb = (long long)b * FSZ;
    const float* fbase = f + bb;
    const float* fend = f + (TOT - 4);

    // lane remap: unit residue (mod 8) injective over stride-8 lane phases
    const int t = tid >> 4;                          // m-tile 0..15
    const int yy = ((tid >> 3) & 1) | ((tid & 7) << 1);  // y row 0..15
    const int m0 = core + 8 * t;
    const int y = 2 + 16 * yt + yy;

    int jlo = 6 - m0; if (jlo < 0) jlo = 0;  // valid m in [6, 474)
    int jhi = 474 - m0; if (jhi > 8) jhi = 8;
    if (y >= DIM - 2) jhi = -1;              // y edge mask

    // unit of (center row, m0-8); all reads are this + compile-time offsets
    const int rc = (yy + 2) * ROWU + 2 * t;

    // precomputed stage chunk global offsets (fixed per thread)
    long long choff[3];
#pragma unroll
    for (int it = 0; it < 3; ++it) {
        int c = it * 256 + tid;
        int row = c / ROWU, col = c - row * ROWU;
        choff[it] = (long long)(gy0 + row) * SY + Gm + 4 * col;
    }
    const bool ch2ok = (512 + tid) < USED_U;

    auto stage = [&](int slab) {
        int slot = slab % SLOTS;
        long long sb = (long long)slab * SX;
#pragma unroll
        for (int it = 0; it < 3; ++it) {
            if (it < 2 || ch2ok) {
                const float* gp = fbase + (sb + choff[it]);
                gp = gp < f ? f : gp;        // clamp buffer ends (masked data)
                gp = gp > fend ? fend : gp;
                __builtin_amdgcn_global_load_lds(
                    (const __attribute__((address_space(1))) unsigned int*)gp,
                    (__attribute__((address_space(3))) unsigned int*)
                        ((__attribute__((address_space(3))) float*)lds
                         + slot * SLICE_F + 4 * (it * 256 + tid)),
                    16, 0, 0);
            }
        }
    };

    for (int d = -2; d <= 2; ++d) stage(X0 + d);
    __syncthreads();

    // FIFO seeds: set A consumed at even steps (x-1 = X0-1), set B at odd (X0)
    F4 fa_xm[4], fa_pp[2], fa_pm[2], fb_xm[4], fb_pp[2], fb_pm[2];
    {
        const float* Sm1 = lds + ((X0 + 5) % SLOTS) * SLICE_F + 4 * rc;
        const float* S0  = lds + ((X0) % SLOTS) * SLICE_F + 4 * rc;
#pragma unroll
        for (int i = 0; i < 4; ++i) {
            fa_xm[i] = *(const F4*)(Sm1 + 4 + 4 * i);
            fb_xm[i] = *(const F4*)(S0 + 4 + 4 * i);
        }
#pragma unroll
        for (int i = 0; i < 2; ++i) {
            fa_pp[i] = *(const F4*)(Sm1 + 4 * ROWU + 8 + 4 * i);
            fa_pm[i] = *(const F4*)(Sm1 - 4 * ROWU + 8 + 4 * i);
            fb_pp[i] = *(const F4*)(S0 + 4 * ROWU + 8 + 4 * i);
            fb_pm[i] = *(const F4*)(S0 - 4 * ROWU + 8 + 4 * i);
        }
    }

    float e = 0.0f;                          // raw energy (x16 scale)

    // one x-step; Fxm/Fpp/Fpm hold the x-1 taps (read 2 steps ago), and are
    // overwritten with this step's x+1 reads (pure renames after unrolling).
    auto step = [&](int x, F4* Fxm, F4* Fpp, F4* Fpm) {
        stage(x + 3);                        // into slot of slab x-3: no race

        const float* L0  = lds + ((x) % SLOTS) * SLICE_F + 4 * rc;
        const float* Lp1 = lds + ((x + 1) % SLOTS) * SLICE_F + 4 * rc;
        const float* Lp2 = lds + ((x + 2) % SLOTS) * SLICE_F + 4 * rc;
        const float* Lm2 = lds + ((x + 4) % SLOTS) * SLICE_F + 4 * rc;

        float C[24], XP[16], YP[16], YM[16];
        F4 X2P[2], X2M[2], Y2P[2], Y2M[2], PPn[2], PMn[2];
#pragma unroll
        for (int i = 0; i < 6; ++i)
            *(F4*)(&C[4 * i]) = *(const F4*)(L0 + 4 * i);
#pragma unroll
        for (int i = 0; i < 4; ++i) {
            *(F4*)(&XP[4 * i]) = *(const F4*)(Lp1 + 4 + 4 * i);
            *(F4*)(&YP[4 * i]) = *(const F4*)(L0 + 4 * ROWU + 4 + 4 * i);
            *(F4*)(&YM[4 * i]) = *(const F4*)(L0 - 4 * ROWU + 4 + 4 * i);
        }
#pragma unroll
        for (int i = 0; i < 2; ++i) {
            X2P[i] = *(const F4*)(Lp2 + 8 + 4 * i);
            X2M[i] = *(const F4*)(Lm2 + 8 + 4 * i);
            Y2P[i] = *(const F4*)(L0 + 8 * ROWU + 8 + 4 * i);
            Y2M[i] = *(const F4*)(L0 - 8 * ROWU + 8 + 4 * i);
            PPn[i] = *(const F4*)(Lp1 + 4 * ROWU + 8 + 4 * i);
            PMn[i] = *(const F4*)(Lp1 - 4 * ROWU + 8 + 4 * i);
        }

#pragma unroll
        for (int j = 0; j < 8; ++j) {
            float ctr2 = 2.0f * C[j + 8];
            float dxx = (X2P[j >> 2][j & 3] + X2M[j >> 2][j & 3]) - ctr2;
            float dyy = (Y2P[j >> 2][j & 3] + Y2M[j >> 2][j & 3]) - ctr2;
            float dzz = (C[j + 14] + C[j + 2]) - ctr2;
            // dxy = (DPP - DMP) - (DPM - DMM); DMP/DMM from FIFO (x-1 slabs)
            float dxy = (PPn[j >> 2][j & 3] - Fpp[j >> 2][j & 3])
                      - (PMn[j >> 2][j & 3] - Fpm[j >> 2][j & 3]);
            float dxz = (XP[j + 7] - Fxm[(j + 7) >> 2][(j + 7) & 3])
                      - (XP[j + 1] - Fxm[(j + 1) >> 2][(j + 1) & 3]);
            float dyz = (YP[j + 7] - YM[j + 7]) - (YP[j + 1] - YM[j + 1]);
            float dd = dxx * dxx + dyy * dyy + dzz * dzz;
            float dc = dxy * dxy + dxz * dxz + dyz * dyz;
            float msk = (j >= jlo && j < jhi) ? 1.0f : 0.0f;
            e += msk * (dd + 2.0f * dc);
        }

        // this step's x+1 data becomes x-1 data two steps later
#pragma unroll
        for (int i = 0; i < 4; ++i) Fxm[i] = *(F4*)(&XP[4 * i]);
#pragma unroll
        for (int i = 0; i < 2; ++i) { Fpp[i] = PPn[i]; Fpm[i] = PMn[i]; }

        __syncthreads();   // drains stage vmcnt + orders slot reuse
    };

    for (int sp = 0; sp < STEPS / 2; ++sp) {
        step(X0 + 2 * sp,     fa_xm, fa_pp, fa_pm);
        step(X0 + 2 * sp + 1, fb_xm, fb_pp, fb_pm);
    }

    // wave reduce -> block reduce -> one atomic per block
#pragma unroll
    for (int off = 32; off > 0; off >>= 1) e += __shfl_down(e, off, 64);

    __shared__ float ws[4];
    int lane = tid & 63;
    int wid = tid >> 6;
    if (lane == 0) ws[wid] = e;
    __syncthreads();
    if (tid == 0) {
        // 0.0625 = (0.25)^2 from the two central-difference factors
        const float inv_count = 0.0625f / (156.0f * 156.0f * 156.0f * 3.0f);
        atomicAdd(&out[b], (ws[0] + ws[1] + ws[2] + ws[3]) * inv_count);
    }
}

extern "C" void kernel_launch(void* const* d_in, const int* in_sizes, int n_in,
                              void* d_out, int out_size, void* d_ws, size_t ws_size,
                              hipStream_t stream) {
    const float* f = (const float*)d_in[0];
    float* out = (float*)d_out;

    hipMemsetAsync(d_out, 0, out_size * sizeof(float), stream);

    be_kernel<<<dim3(NBLK), dim3(256), 0, stream>>>(f, out);
}